// Round 14
// baseline (117.006 us; speedup 1.0000x reference)
//
#include <hip/hip_runtime.h>

typedef unsigned short u16;
typedef unsigned int u32;
typedef __attribute__((ext_vector_type(8))) short short8;
typedef __attribute__((ext_vector_type(4))) float f32x4;
typedef __attribute__((ext_vector_type(2))) unsigned int u32x2;
typedef __attribute__((ext_vector_type(4))) unsigned short u16x4;
typedef __attribute__((ext_vector_type(8))) unsigned short u16x8;

#define AS1 __attribute__((address_space(1)))
#define AS3 __attribute__((address_space(3)))

__device__ __forceinline__ u16 f2bf(float f) {
  u32 u = __builtin_bit_cast(u32, f);
  u32 r = u + 0x7FFFu + ((u >> 16) & 1u);
  return (u16)(r >> 16);
}
__device__ __forceinline__ float bf2f(u16 h) {
  u32 u = ((u32)h) << 16;
  return __builtin_bit_cast(float, u);
}
__device__ __forceinline__ void gload_lds16(const void* g, void* l) {
  __builtin_amdgcn_global_load_lds((AS1 void*)g, (AS3 void*)l, 16, 0, 0);
}
__device__ __forceinline__ float fexp2(float x) {
  float r;
  asm("v_exp_f32 %0, %1" : "=v"(r) : "v"(x));
  return r;
}

#define QSCALE 0.04508422002778011f   // (0.25/8) * log2(e)

// ---------------- fused pre-pass: 3x fp32->bf16 convert + RoPE table ----------------
__device__ __forceinline__ void cvt_body(const float* __restrict__ src, u16* __restrict__ dst,
                                         int i) {
  float4 v = ((const float4*)src)[i];
  u16x4 o;
  o[0] = f2bf(v.x); o[1] = f2bf(v.y); o[2] = f2bf(v.z); o[3] = f2bf(v.w);
  ((u16x4*)dst)[i] = o;
}

__global__ __launch_bounds__(256)
void pre_kernel(const float* __restrict__ x, const float* __restrict__ w1,
                const float* __restrict__ w2, const int* __restrict__ pos,
                u16* __restrict__ x_bf, u16* __restrict__ w1_bf, u16* __restrict__ w2_bf,
                float* __restrict__ tab) {
  int bid = blockIdx.x;
  int t = threadIdx.x;
  if (bid < 4096) {
    cvt_body(x, x_bf, bid * 256 + t);
  } else if (bid < 7168) {
    cvt_body(w1, w1_bf, (bid - 4096) * 256 + t);
  } else if (bid < 8192) {
    cvt_body(w2, w2_bf, (bid - 7168) * 256 + t);
  } else {
    int idx = (bid - 8192) * 256 + t;      // over B*L*32 = 131072
    int i = idx & 31;
    int bl = idx >> 5;
    float p = (float)pos[bl];
    float inv_freq = 1.0f / powf(10000.0f, (2.0f * (float)i) / 64.0f);
    float ang = p * inv_freq;
    tab[(size_t)bl * 64 + i] = cosf(ang);
    tab[(size_t)bl * 64 + 32 + i] = sinf(ang);
  }
}

// ---------------- GEMM 256x256 deep-pipeline (gemm1): C[M,N]=A[M,K]*B[N,K]^T, bf16 out --
// 8 waves (2M x 4N), BK=64, LDS 128 KB = 2 dbuf x (A 256x64 + B 256x64). Per K-tile:
// 4 phases x {stage-next (ph 0-1) -> 12 ds_read_b128 -> 16 MFMA quadrant}; one
// vmcnt(0)+barrier per tile. Staging targets the INACTIVE dbuf (race-free: its readers
// finished before the previous boundary barrier); issue->drain spans ~3 phases.
__global__ __launch_bounds__(512)
void gemm256_kernel(const u16* __restrict__ A, const u16* __restrict__ Bw,
                    u16* __restrict__ C, int M, int N, int K, int NXT) {
  __shared__ alignas(16) u16 Abuf[2][256 * 64];   // 64 KB
  __shared__ alignas(16) u16 Bbuf[2][256 * 64];   // 64 KB
  const int tid = threadIdx.x;
  const int lane = tid & 63, wave = tid >> 6;     // 8 waves
  const int wm = wave >> 2, wn = wave & 3;        // 2 x 4 wave grid
  const int lin = (blockIdx.x & 7) * (gridDim.x >> 3) + (blockIdx.x >> 3);  // XCD-chunked
  const int m0 = (lin / NXT) * 256, n0 = (lin % NXT) * 256;
  const int r = lane & 15, g = lane >> 4;

  const int srow_base = tid >> 3;                 // 0..63
  const int sslot = tid & 7;

  f32x4 acc[8][4] = {};
  const int nk = K >> 6;

#define STAGE_C(kt_, d_, c_) do { \
    int row_ = (c_) * 64 + srow_base; \
    int ss_ = sslot ^ (row_ & 7); \
    gload_lds16(A + (size_t)(m0 + row_) * K + ((kt_) << 6) + ss_ * 8, \
                (char*)Abuf[d_] + (c_) * 8192 + wave * 1024); \
    gload_lds16(Bw + (size_t)(n0 + row_) * K + ((kt_) << 6) + ss_ * 8, \
                (char*)Bbuf[d_] + (c_) * 8192 + wave * 1024); \
  } while (0)

  // prologue: tile 0 -> dbuf 0 (8 loads/thread)
  STAGE_C(0, 0, 0); STAGE_C(0, 0, 1); STAGE_C(0, 0, 2); STAGE_C(0, 0, 3);
  asm volatile("s_waitcnt vmcnt(0)" ::: "memory");
  __builtin_amdgcn_s_barrier();

  for (int kt = 0; kt < nk; ++kt) {
    const int d = kt & 1;
    const char* Ac = (const char*)Abuf[d];
    const char* Bc = (const char*)Bbuf[d];
#pragma unroll
    for (int p = 0; p < 4; ++p) {
      if (p < 2 && kt + 1 < nk) {               // stage tile kt+1 into inactive dbuf
        STAGE_C(kt + 1, d ^ 1, 2 * p);
        STAGE_C(kt + 1, d ^ 1, 2 * p + 1);
      }
      const int mq = p >> 1, nq = p & 1;        // C-quadrant for this phase
      short8 af[4][2], bfr[2][2];
#pragma unroll
      for (int ml = 0; ml < 4; ++ml)
#pragma unroll
        for (int kk = 0; kk < 2; ++kk) {
          int row = wm * 128 + (mq * 4 + ml) * 16 + r;
          af[ml][kk] = *(const short8*)(Ac + row * 128 + (((kk * 4 + g) ^ (row & 7)) << 4));
        }
#pragma unroll
      for (int nl = 0; nl < 2; ++nl)
#pragma unroll
        for (int kk = 0; kk < 2; ++kk) {
          int row = wn * 64 + (nq * 2 + nl) * 16 + r;
          bfr[nl][kk] = *(const short8*)(Bc + row * 128 + (((kk * 4 + g) ^ (row & 7)) << 4));
        }
      __builtin_amdgcn_s_setprio(1);
#pragma unroll
      for (int ml = 0; ml < 4; ++ml)
#pragma unroll
        for (int nl = 0; nl < 2; ++nl)
#pragma unroll
          for (int kk = 0; kk < 2; ++kk)
            acc[mq * 4 + ml][nq * 2 + nl] =
                __builtin_amdgcn_mfma_f32_16x16x32_bf16(af[ml][kk], bfr[nl][kk],
                                                        acc[mq * 4 + ml][nq * 2 + nl],
                                                        0, 0, 0);
      __builtin_amdgcn_s_setprio(0);
    }
    if (kt + 1 < nk) {
      asm volatile("s_waitcnt vmcnt(0)" ::: "memory");  // tile kt+1 landed (issued ph 0-1)
      __builtin_amdgcn_s_barrier();                     // all readers of dbuf d done
    }
  }
#undef STAGE_C

  // epilogue: bf16 store
#pragma unroll
  for (int m = 0; m < 8; ++m) {
    int rg = m0 + wm * 128 + m * 16 + g * 4;
#pragma unroll
    for (int n = 0; n < 4; ++n) {
      int cg = n0 + wn * 64 + n * 16 + r;
#pragma unroll
      for (int j = 0; j < 4; ++j)
        C[(size_t)(rg + j) * N + cg] = f2bf(acc[m][n][j]);
    }
  }
}

// ---------------- GEMM 128x64 (proj): 512 blocks -> 2/CU ----------------
__global__ __launch_bounds__(256)
void gemm_bt64_kernel(const u16* __restrict__ A, const u16* __restrict__ Bw,
                      float* __restrict__ Cout, const float* __restrict__ bias,
                      int M, int N, int K, int NXT) {
  __shared__ alignas(16) u16 As[128 * 64];
  __shared__ alignas(16) u16 Bs[64 * 64];
  const int tid = threadIdx.x;
  const int lane = tid & 63, wave = tid >> 6;
  const int wr = wave >> 1, wc = wave & 1;
  const int nblk = gridDim.x;
  const int lin = (blockIdx.x & 7) * (nblk >> 3) + (blockIdx.x >> 3);
  const int m0 = (lin / NXT) * 128, n0 = (lin % NXT) * 64;
  const int r = lane & 15, g = lane >> 4;

  f32x4 acc[4][2] = {};

  const int nk = K >> 6;
  for (int kt = 0; kt < nk; ++kt) {
    const int k0 = kt << 6;
#pragma unroll
    for (int c = 0; c < 4; ++c) {
      int i = c * 256 + tid;
      int row = i >> 3, slot = i & 7;
      int ss = slot ^ (row & 7);
      const u16* gA = A + (size_t)(m0 + row) * K + k0 + ss * 8;
      void* lA = (char*)As + c * 4096 + wave * 1024;
      gload_lds16(gA, lA);
    }
#pragma unroll
    for (int c = 0; c < 2; ++c) {
      int i = c * 256 + tid;
      int row = i >> 3, slot = i & 7;
      int ss = slot ^ (row & 7);
      const u16* gB = Bw + (size_t)(n0 + row) * K + k0 + ss * 8;
      void* lB = (char*)Bs + c * 4096 + wave * 1024;
      gload_lds16(gB, lB);
    }
    __syncthreads();
#pragma unroll
    for (int kk = 0; kk < 2; ++kk) {
      short8 af[4], bf[2];
#pragma unroll
      for (int m = 0; m < 4; ++m) {
        int row = wr * 64 + m * 16 + r;
        int byte = row * 128 + (((kk * 4 + g) ^ (row & 7)) << 4);
        af[m] = *(const short8*)((const char*)As + byte);
      }
#pragma unroll
      for (int n = 0; n < 2; ++n) {
        int row = wc * 32 + n * 16 + r;
        int byte = row * 128 + (((kk * 4 + g) ^ (row & 7)) << 4);
        bf[n] = *(const short8*)((const char*)Bs + byte);
      }
#pragma unroll
      for (int m = 0; m < 4; ++m)
#pragma unroll
        for (int n = 0; n < 2; ++n)
          acc[m][n] = __builtin_amdgcn_mfma_f32_16x16x32_bf16(af[m], bf[n], acc[m][n], 0, 0, 0);
    }
    __syncthreads();
  }

#pragma unroll
  for (int m = 0; m < 4; ++m) {
    int rg = m0 + wr * 64 + m * 16 + g * 4;
#pragma unroll
    for (int n = 0; n < 2; ++n) {
      int cg = n0 + wc * 32 + n * 16 + r;
      float bv = bias[cg];
#pragma unroll
      for (int j = 0; j < 4; ++j)
        Cout[(size_t)(rg + j) * N + cg] = acc[m][n][j] + bv;
    }
  }
}

// ---------------- fused RoPE-pack + V-transpose ----------------
__global__ __launch_bounds__(256)
void mid_kernel(const u16* __restrict__ qkv, const float* __restrict__ tab,
                const float* __restrict__ q_bias, const float* __restrict__ v_bias,
                u16* __restrict__ Qo, u16* __restrict__ Ko, u16* __restrict__ vt) {
  __shared__ alignas(16) u16 tile[64][72];
  int bid = blockIdx.x;
  int t = threadIdx.x;
  if (bid < 4096) {
    int bl = bid;                     // b*2048 + l
    int b = bl >> 11, l = bl & 2047;
    const float* tr = tab + (size_t)bl * 64;
    const u16* base = qkv + (size_t)bl * 3072;
#pragma unroll
    for (int pp = 0; pp < 2; ++pp) {
      int p = t + pp * 256;           // 0..511
      int h = p >> 5, d = p & 31;
      float c = tr[d], s = tr[32 + d];
      size_t o = ((size_t)(b * 16 + h) * 2048 + l) * 64 + d;
      float x1 = bf2f(base[h * 64 + d]) + q_bias[h * 64 + d];
      float x2 = bf2f(base[h * 64 + d + 32]) + q_bias[h * 64 + d + 32];
      Qo[o]      = f2bf((x1 * c - x2 * s) * QSCALE);
      Qo[o + 32] = f2bf((x2 * c + x1 * s) * QSCALE);
      x1 = bf2f(base[1024 + h * 64 + d]);
      x2 = bf2f(base[1024 + h * 64 + d + 32]);
      Ko[o]      = f2bf(x1 * c - x2 * s);
      Ko[o + 32] = f2bf(x2 * c + x1 * s);
    }
  } else {
    int bid2 = bid - 4096;
    int bh = bid2 >> 5;
    int b = bh >> 4, h = bh & 15;
    int l0 = (bid2 & 31) * 64;
    int rr = t >> 2;
    int c0 = (t & 3) * 16;
    const u16* src = qkv + ((size_t)(b * 2048 + l0 + rr)) * 3072 + 2048 + h * 64 + c0;
    u16x8 a = *(const u16x8*)src;
    u16x8 bb = *(const u16x8*)(src + 8);
#pragma unroll
    for (int i = 0; i < 8; ++i) {
      a[i]  = f2bf(bf2f(a[i])  + v_bias[h * 64 + c0 + i]);
      bb[i] = f2bf(bf2f(bb[i]) + v_bias[h * 64 + c0 + 8 + i]);
    }
    *(u16x8*)&tile[rr][c0] = a;
    *(u16x8*)&tile[rr][c0 + 8] = bb;
    __syncthreads();
    int d = t >> 2;
    int lc = (t & 3) * 16;
    u16x8 o1, o2;
#pragma unroll
    for (int i = 0; i < 8; ++i) {
      o1[i] = tile[lc + i][d];
      o2[i] = tile[lc + 8 + i][d];
    }
    u16* dst = vt + ((size_t)bh * 64 + d) * 2048 + l0 + lc;
    *(u16x8*)dst = o1;
    *(u16x8*)(dst + 8) = o2;
  }
}

// ---------------- causal flash attention: 2-tile super-steps (R13, unchanged) ----------
__global__ __launch_bounds__(512)
void attn_kernel(const u16* __restrict__ Q, const u16* __restrict__ Kmat,
                 const u16* __restrict__ Vt, u16* __restrict__ O) {
  __shared__ alignas(16) u16 Ks[4][64 * 64];   // 32 KB
  __shared__ alignas(16) u16 Vs[4][64 * 64];   // 32 KB
  __shared__ alignas(16) u16 Pbuf[8][1024];    // 16 KB
  const int tid = threadIdx.x;
  const int lane = tid & 63;
  const int wave = tid >> 6;                   // 0..7
  const int id = blockIdx.x;
  const int xcd = id & 7, rank = id >> 3;      // rank 0..63
  const int bh = xcd + 8 * (rank & 3);         // 4 bh per XCD -> K/V L2-resident
  const int xqA = 31 - (rank >> 2);            // 16..31, heavy blocks first
  const int wt = wave >> 2;                    // 0 = tile A, 1 = tile B
  const int xq = wt ? (xqA - 16) : xqA;
  const int ntA = xqA + 1;                     // block-level steps (17..32)
  const int nt = xq + 1;                       // this wave's active steps
  const int b = bh >> 4, h = bh & 15;
  const int r = lane & 15, g = lane >> 4;

  const u16* Kb = Kmat + (size_t)bh * 2048 * 64;
  const u16* Vb = Vt + (size_t)bh * 64 * 2048;

  const int srow = wave * 8 + (lane >> 3);
  const int sslot = (lane & 7) ^ (srow & 7);

#define STAGE(tt, bb) do { \
    gload_lds16(Kb + ((size_t)((tt) * 64 + srow)) * 64 + sslot * 8, \
                (char*)Ks[bb] + wave * 1024); \
    gload_lds16(Vb + (size_t)srow * 2048 + (tt) * 64 + sslot * 8, \
                (char*)Vs[bb] + wave * 1024); \
  } while (0)

  u16* Pw = Pbuf[wave];
  const int qrow0 = xq * 64 + (wave & 3) * 16;
  const u16* Qb = Q + ((size_t)bh * 2048 + qrow0) * 64;

  short8 qf[2];
#pragma unroll
  for (int kk = 0; kk < 2; ++kk)
    qf[kk] = *(const short8*)(Qb + r * 64 + kk * 32 + g * 8);

  short8 ones;
#pragma unroll
  for (int i = 0; i < 8; ++i) ones[i] = (short)0x3F80;

  f32x4 o_acc[4] = {};
  f32x4 l_acc = {};

  STAGE(0, 0);
  STAGE(1, 1);
  asm volatile("s_waitcnt vmcnt(0)" ::: "memory");
  __builtin_amdgcn_s_barrier();

  const int nss = (ntA + 1) >> 1;
  for (int ss = 0; ss < nss; ++ss) {
    const int t0 = 2 * ss, t1 = t0 + 1;
    const int cb = 2 * (ss & 1);
    const int sb = 2 * ((ss + 1) & 1);

    if (t0 + 2 < ntA) STAGE(t0 + 2, sb);
    if (t0 + 3 < ntA) STAGE(t0 + 3, sb + 1);

    const bool a0 = (t0 < nt);
    const bool a1 = (t1 < nt);

    f32x4 s0[4] = {}, s1[4] = {};
    __builtin_amdgcn_s_setprio(1);
    if (a0) {
      const char* Kc = (const char*)Ks[cb];
#pragma unroll
      for (int ct = 0; ct < 4; ++ct)
#pragma unroll
        for (int kk = 0; kk < 2; ++kk) {
          int row = ct * 16 + r;
          int byte = row * 128 + (((kk * 4 + g) ^ (row & 7)) << 4);
          short8 kf = *(const short8*)(Kc + byte);
          s0[ct] = __builtin_amdgcn_mfma_f32_16x16x32_bf16(kf, qf[kk], s0[ct], 0, 0, 0);
        }
    }
    if (a1) {
      const char* Kc = (const char*)Ks[cb + 1];
#pragma unroll
      for (int ct = 0; ct < 4; ++ct)
#pragma unroll
        for (int kk = 0; kk < 2; ++kk) {
          int row = ct * 16 + r;
          int byte = row * 128 + (((kk * 4 + g) ^ (row & 7)) << 4);
          short8 kf = *(const short8*)(Kc + byte);
          s1[ct] = __builtin_amdgcn_mfma_f32_16x16x32_bf16(kf, qf[kk], s1[ct], 0, 0, 0);
        }
    }
    __builtin_amdgcn_s_setprio(0);

    if (a0 && t0 * 64 + 63 > qrow0) {
      int qrow = qrow0 + r;
#pragma unroll
      for (int ct = 0; ct < 4; ++ct)
#pragma unroll
        for (int j = 0; j < 4; ++j) {
          int kv = t0 * 64 + ct * 16 + 4 * g + j;
          if (kv > qrow) s0[ct][j] = -1e30f;
        }
    }
    if (a1 && t1 * 64 + 63 > qrow0) {
      int qrow = qrow0 + r;
#pragma unroll
      for (int ct = 0; ct < 4; ++ct)
#pragma unroll
        for (int j = 0; j < 4; ++j) {
          int kv = t1 * 64 + ct * 16 + 4 * g + j;
          if (kv > qrow) s1[ct][j] = -1e30f;
        }
    }

    u32x2 pk0[4], pk1[4];
    if (a0) {
#pragma unroll
      for (int ct = 0; ct < 4; ++ct) {
        float p0 = fexp2(s0[ct][0]);
        float p1 = fexp2(s0[ct][1]);
        float p2 = fexp2(s0[ct][2]);
        float p3 = fexp2(s0[ct][3]);
        asm("v_cvt_pk_bf16_f32 %0, %1, %2" : "=v"(pk0[ct][0]) : "v"(p0), "v"(p1));
        asm("v_cvt_pk_bf16_f32 %0, %1, %2" : "=v"(pk0[ct][1]) : "v"(p2), "v"(p3));
      }
    }
    if (a1) {
#pragma unroll
      for (int ct = 0; ct < 4; ++ct) {
        float p0 = fexp2(s1[ct][0]);
        float p1 = fexp2(s1[ct][1]);
        float p2 = fexp2(s1[ct][2]);
        float p3 = fexp2(s1[ct][3]);
        asm("v_cvt_pk_bf16_f32 %0, %1, %2" : "=v"(pk1[ct][0]) : "v"(p0), "v"(p1));
        asm("v_cvt_pk_bf16_f32 %0, %1, %2" : "=v"(pk1[ct][1]) : "v"(p2), "v"(p3));
      }
    }

    if (a0) {
#pragma unroll
      for (int ct = 0; ct < 4; ++ct) {
        int byte = r * 128 + ((32 * ct + 8 * g) ^ ((r & 7) << 4));
        *(u32x2*)((char*)Pw + byte) = pk0[ct];
      }
      const char* Vc = (const char*)Vs[cb];
      __builtin_amdgcn_s_setprio(1);
#pragma unroll
      for (int kk = 0; kk < 2; ++kk) {
        int byte = r * 128 + (((kk * 4 + g) ^ (r & 7)) << 4);
        short8 pf = *(const short8*)((const char*)Pw + byte);
        l_acc = __builtin_amdgcn_mfma_f32_16x16x32_bf16(pf, ones, l_acc, 0, 0, 0);
#pragma unroll
        for (int n = 0; n < 4; ++n) {
          int row = n * 16 + r;
          int vbyte = row * 128 + (((kk * 4 + g) ^ (row & 7)) << 4);
          short8 vf = *(const short8*)(Vc + vbyte);
          o_acc[n] = __builtin_amdgcn_mfma_f32_16x16x32_bf16(pf, vf, o_acc[n], 0, 0, 0);
        }
      }
      __builtin_amdgcn_s_setprio(0);
    }

    if (a1) {
#pragma unroll
      for (int ct = 0; ct < 4; ++ct) {
        int byte = r * 128 + ((32 * ct + 8 * g) ^ ((r & 7) << 4));
        *(u32x2*)((char*)Pw + byte) = pk1[ct];
      }
      const char* Vc = (const char*)Vs[cb + 1];
      __builtin_amdgcn_s_setprio(1);
#pragma unroll
      for (int kk = 0; kk < 2; ++kk) {
        int byte = r * 128 + (((kk * 4 + g) ^ (r & 7)) << 4);
        short8 pf = *(const short8*)((const char*)Pw + byte);
        l_acc = __builtin_amdgcn_mfma_f32_16x16x32_bf16(pf, ones, l_acc, 0, 0, 0);
#pragma unroll
        for (int n = 0; n < 4; ++n) {
          int row = n * 16 + r;
          int vbyte = row * 128 + (((kk * 4 + g) ^ (row & 7)) << 4);
          short8 vf = *(const short8*)(Vc + vbyte);
          o_acc[n] = __builtin_amdgcn_mfma_f32_16x16x32_bf16(pf, vf, o_acc[n], 0, 0, 0);
        }
      }
      __builtin_amdgcn_s_setprio(0);
    }

    if (ss + 1 < nss) {
      asm volatile("s_waitcnt vmcnt(0)" ::: "memory");
      __builtin_amdgcn_s_barrier();
    }
  }
#undef STAGE

  float ij[4];
#pragma unroll
  for (int j = 0; j < 4; ++j) ij[j] = 1.0f / l_acc[j];
#pragma unroll
  for (int n = 0; n < 4; ++n)
#pragma unroll
    for (int j = 0; j < 4; ++j) {
      size_t idx = ((size_t)b * 2048 + qrow0 + 4 * g + j) * 1024 + h * 64 + n * 16 + r;
      O[idx] = f2bf(o_acc[n][j] * ij[j]);
    }
}

// ---------------- launcher ----------------
extern "C" void kernel_launch(void* const* d_in, const int* in_sizes, int n_in,
                              void* d_out, int out_size, void* d_ws, size_t ws_size,
                              hipStream_t stream) {
  const float* x      = (const float*)d_in[0];
  const int*   pos    = (const int*)d_in[2];
  const float* qkv_w  = (const float*)d_in[3];
  const float* q_bias = (const float*)d_in[4];
  const float* v_bias = (const float*)d_in[5];
  const float* proj_w = (const float*)d_in[6];
  const float* proj_b = (const float*)d_in[7];
  float* out = (float*)d_out;

  char* ws = (char*)d_ws;
  u16* x_bf    = (u16*)(ws + 0);          //  8 MB  [4096][1024]
  u16* w1_bf   = (u16*)(ws + 8388608);    //  6 MB  [3072][1024]
  u16* w2_bf   = (u16*)(ws + 14680064);   //  2 MB  [1024][1024]
  u16* qkv_bf  = (u16*)(ws + 16777216);   // 24 MB  [4096][3072]
  u16* q_bf    = (u16*)(ws + 41943040);   //  8 MB  [B,H,L,D]
  u16* k_bf    = (u16*)(ws + 50331648);   //  8 MB  [B,H,L,D]
  u16* vt_bf   = (u16*)(ws + 58720256);   //  8 MB  [B,H,D,L]
  u16* attn_bf = (u16*)(ws + 67108864);   //  8 MB  [4096][1024]
  float* tab   = (float*)(ws + 75497472); //  1 MB  [B*L][64]

  pre_kernel<<<8704, 256, 0, stream>>>(x, qkv_w, proj_w, pos, x_bf, w1_bf, w2_bf, tab);
  gemm256_kernel<<<192, 512, 0, stream>>>(x_bf, w1_bf, qkv_bf, 4096, 3072, 1024, 12);
  mid_kernel<<<5120, 256, 0, stream>>>(qkv_bf, tab, q_bias, v_bias, q_bf, k_bf, vt_bf);
  attn_kernel<<<512, 512, 0, stream>>>(q_bf, k_bf, vt_bf, attn_bf);
  gemm_bt64_kernel<<<512, 256, 0, stream>>>(attn_bf, w2_bf, out, proj_b,
                                            4096, 1024, 1024, 16);
}

// Round 15
// 109.816 us; speedup vs baseline: 1.0655x; 1.0655x over previous
//
#include <hip/hip_runtime.h>

typedef unsigned short u16;
typedef unsigned int u32;
typedef __attribute__((ext_vector_type(8))) short short8;
typedef __attribute__((ext_vector_type(4))) float f32x4;
typedef __attribute__((ext_vector_type(2))) unsigned int u32x2;
typedef __attribute__((ext_vector_type(4))) unsigned short u16x4;
typedef __attribute__((ext_vector_type(8))) unsigned short u16x8;

#define AS1 __attribute__((address_space(1)))
#define AS3 __attribute__((address_space(3)))

__device__ __forceinline__ u16 f2bf(float f) {
  u32 u = __builtin_bit_cast(u32, f);
  u32 r = u + 0x7FFFu + ((u >> 16) & 1u);
  return (u16)(r >> 16);
}
__device__ __forceinline__ float bf2f(u16 h) {
  u32 u = ((u32)h) << 16;
  return __builtin_bit_cast(float, u);
}
__device__ __forceinline__ void gload_lds16(const void* g, void* l) {
  __builtin_amdgcn_global_load_lds((AS1 void*)g, (AS3 void*)l, 16, 0, 0);
}
__device__ __forceinline__ float fexp2(float x) {
  float r;
  asm("v_exp_f32 %0, %1" : "=v"(r) : "v"(x));
  return r;
}

#define QSCALE 0.04508422002778011f   // (0.25/8) * log2(e)

// ---------------- fused pre-pass: 3x fp32->bf16 convert + RoPE table ----------------
__device__ __forceinline__ void cvt_body(const float* __restrict__ src, u16* __restrict__ dst,
                                         int i) {
  float4 v = ((const float4*)src)[i];
  u16x4 o;
  o[0] = f2bf(v.x); o[1] = f2bf(v.y); o[2] = f2bf(v.z); o[3] = f2bf(v.w);
  ((u16x4*)dst)[i] = o;
}

__global__ __launch_bounds__(256)
void pre_kernel(const float* __restrict__ x, const float* __restrict__ w1,
                const float* __restrict__ w2, const int* __restrict__ pos,
                u16* __restrict__ x_bf, u16* __restrict__ w1_bf, u16* __restrict__ w2_bf,
                float* __restrict__ tab) {
  int bid = blockIdx.x;
  int t = threadIdx.x;
  if (bid < 4096) {
    cvt_body(x, x_bf, bid * 256 + t);
  } else if (bid < 7168) {
    cvt_body(w1, w1_bf, (bid - 4096) * 256 + t);
  } else if (bid < 8192) {
    cvt_body(w2, w2_bf, (bid - 7168) * 256 + t);
  } else {
    int idx = (bid - 8192) * 256 + t;      // over B*L*32 = 131072
    int i = idx & 31;
    int bl = idx >> 5;
    float p = (float)pos[bl];
    float inv_freq = 1.0f / powf(10000.0f, (2.0f * (float)i) / 64.0f);
    float ang = p * inv_freq;
    tab[(size_t)bl * 64 + i] = cosf(ang);
    tab[(size_t)bl * 64 + 32 + i] = sinf(ang);
  }
}

// ---------------- GEMM 128x128: C[M,N] = A[M,K]*B[N,K]^T (+bias opt) ----------------
template <bool OUT_BF16>
__global__ __launch_bounds__(256)
void gemm_bt_kernel(const u16* __restrict__ A, const u16* __restrict__ Bw,
                    void* __restrict__ Cout, const float* __restrict__ bias,
                    int M, int N, int K, int NXT) {
  __shared__ alignas(16) u16 As[128 * 64];
  __shared__ alignas(16) u16 Bs[128 * 64];
  const int tid = threadIdx.x;
  const int lane = tid & 63, wave = tid >> 6;
  const int wr = wave >> 1, wc = wave & 1;
  const int nblk = gridDim.x;
  const int lin = (blockIdx.x & 7) * (nblk >> 3) + (blockIdx.x >> 3);  // XCD-chunked
  const int m0 = (lin / NXT) * 128, n0 = (lin % NXT) * 128;
  const int r = lane & 15, g = lane >> 4;

  f32x4 acc[4][4] = {};

  const int nk = K >> 6;
  for (int kt = 0; kt < nk; ++kt) {
    const int k0 = kt << 6;
#pragma unroll
    for (int c = 0; c < 4; ++c) {
      int i = c * 256 + tid;
      int row = i >> 3, slot = i & 7;
      int ss = slot ^ (row & 7);                       // inverse-swizzled source
      const u16* gA = A + (size_t)(m0 + row) * K + k0 + ss * 8;
      const u16* gB = Bw + (size_t)(n0 + row) * K + k0 + ss * 8;
      void* lA = (char*)As + c * 4096 + wave * 1024;
      void* lB = (char*)Bs + c * 4096 + wave * 1024;
      gload_lds16(gA, lA);
      gload_lds16(gB, lB);
    }
    __syncthreads();
#pragma unroll
    for (int kk = 0; kk < 2; ++kk) {
      short8 af[4], bf[4];
#pragma unroll
      for (int m = 0; m < 4; ++m) {
        int row = wr * 64 + m * 16 + r;
        int byte = row * 128 + (((kk * 4 + g) ^ (row & 7)) << 4);
        af[m] = *(const short8*)((const char*)As + byte);
      }
#pragma unroll
      for (int n = 0; n < 4; ++n) {
        int row = wc * 64 + n * 16 + r;
        int byte = row * 128 + (((kk * 4 + g) ^ (row & 7)) << 4);
        bf[n] = *(const short8*)((const char*)Bs + byte);
      }
#pragma unroll
      for (int m = 0; m < 4; ++m)
#pragma unroll
        for (int n = 0; n < 4; ++n)
          acc[m][n] = __builtin_amdgcn_mfma_f32_16x16x32_bf16(af[m], bf[n], acc[m][n], 0, 0, 0);
    }
    __syncthreads();
  }

  if constexpr (OUT_BF16) {
    u16* C = (u16*)Cout;
#pragma unroll
    for (int m = 0; m < 4; ++m) {
      int rg = m0 + wr * 64 + m * 16 + g * 4;
#pragma unroll
      for (int n = 0; n < 4; ++n) {
        int cg = n0 + wc * 64 + n * 16 + r;
#pragma unroll
        for (int j = 0; j < 4; ++j)
          C[(size_t)(rg + j) * N + cg] = f2bf(acc[m][n][j]);
      }
    }
  } else {
    float* C = (float*)Cout;
#pragma unroll
    for (int m = 0; m < 4; ++m) {
      int rg = m0 + wr * 64 + m * 16 + g * 4;
#pragma unroll
      for (int n = 0; n < 4; ++n) {
        int cg = n0 + wc * 64 + n * 16 + r;
        float bv = bias[cg];
#pragma unroll
        for (int j = 0; j < 4; ++j)
          C[(size_t)(rg + j) * N + cg] = acc[m][n][j] + bv;
      }
    }
  }
}

// ---------------- GEMM 128x64 (proj): 512 blocks -> 2/CU ----------------
__global__ __launch_bounds__(256)
void gemm_bt64_kernel(const u16* __restrict__ A, const u16* __restrict__ Bw,
                      float* __restrict__ Cout, const float* __restrict__ bias,
                      int M, int N, int K, int NXT) {
  __shared__ alignas(16) u16 As[128 * 64];
  __shared__ alignas(16) u16 Bs[64 * 64];
  const int tid = threadIdx.x;
  const int lane = tid & 63, wave = tid >> 6;
  const int wr = wave >> 1, wc = wave & 1;
  const int nblk = gridDim.x;
  const int lin = (blockIdx.x & 7) * (nblk >> 3) + (blockIdx.x >> 3);
  const int m0 = (lin / NXT) * 128, n0 = (lin % NXT) * 64;
  const int r = lane & 15, g = lane >> 4;

  f32x4 acc[4][2] = {};

  const int nk = K >> 6;
  for (int kt = 0; kt < nk; ++kt) {
    const int k0 = kt << 6;
#pragma unroll
    for (int c = 0; c < 4; ++c) {
      int i = c * 256 + tid;
      int row = i >> 3, slot = i & 7;
      int ss = slot ^ (row & 7);
      const u16* gA = A + (size_t)(m0 + row) * K + k0 + ss * 8;
      void* lA = (char*)As + c * 4096 + wave * 1024;
      gload_lds16(gA, lA);
    }
#pragma unroll
    for (int c = 0; c < 2; ++c) {
      int i = c * 256 + tid;
      int row = i >> 3, slot = i & 7;
      int ss = slot ^ (row & 7);
      const u16* gB = Bw + (size_t)(n0 + row) * K + k0 + ss * 8;
      void* lB = (char*)Bs + c * 4096 + wave * 1024;
      gload_lds16(gB, lB);
    }
    __syncthreads();
#pragma unroll
    for (int kk = 0; kk < 2; ++kk) {
      short8 af[4], bf[2];
#pragma unroll
      for (int m = 0; m < 4; ++m) {
        int row = wr * 64 + m * 16 + r;
        int byte = row * 128 + (((kk * 4 + g) ^ (row & 7)) << 4);
        af[m] = *(const short8*)((const char*)As + byte);
      }
#pragma unroll
      for (int n = 0; n < 2; ++n) {
        int row = wc * 32 + n * 16 + r;
        int byte = row * 128 + (((kk * 4 + g) ^ (row & 7)) << 4);
        bf[n] = *(const short8*)((const char*)Bs + byte);
      }
#pragma unroll
      for (int m = 0; m < 4; ++m)
#pragma unroll
        for (int n = 0; n < 2; ++n)
          acc[m][n] = __builtin_amdgcn_mfma_f32_16x16x32_bf16(af[m], bf[n], acc[m][n], 0, 0, 0);
    }
    __syncthreads();
  }

#pragma unroll
  for (int m = 0; m < 4; ++m) {
    int rg = m0 + wr * 64 + m * 16 + g * 4;
#pragma unroll
    for (int n = 0; n < 2; ++n) {
      int cg = n0 + wc * 32 + n * 16 + r;
      float bv = bias[cg];
#pragma unroll
      for (int j = 0; j < 4; ++j)
        Cout[(size_t)(rg + j) * N + cg] = acc[m][n][j] + bv;
    }
  }
}

// ---------------- fused RoPE-pack (vectorized) + V-transpose ----------------
// RoPE part: 256 threads = 2 tensors x 16 heads x 8 d-blocks; each thread does 4 RoPE
// pairs with u16x4/float4 vector accesses (was 16 scalar loads + 16 scalar stores).
__global__ __launch_bounds__(256)
void mid_kernel(const u16* __restrict__ qkv, const float* __restrict__ tab,
                const float* __restrict__ q_bias, const float* __restrict__ v_bias,
                u16* __restrict__ Qo, u16* __restrict__ Ko, u16* __restrict__ vt) {
  __shared__ alignas(16) u16 tile[64][72];
  int bid = blockIdx.x;
  int t = threadIdx.x;
  if (bid < 4096) {
    int bl = bid;                     // b*2048 + l
    int b = bl >> 11, l = bl & 2047;
    const float* tr = tab + (size_t)bl * 64;
    const u16* base = qkv + (size_t)bl * 3072;
    const int tensor = t >> 7;        // 0 = q, 1 = k
    const int rem = t & 127;
    const int h = rem >> 3;           // 0..15
    const int d0 = (rem & 7) * 4;     // 0,4,..,28
    const u16* src = base + tensor * 1024 + h * 64 + d0;
    u16x4 a1 = *(const u16x4*)src;
    u16x4 a2 = *(const u16x4*)(src + 32);
    float4 vc = *(const float4*)(tr + d0);
    float4 vs = *(const float4*)(tr + 32 + d0);
    float4 b1 = {0.f, 0.f, 0.f, 0.f}, b2 = b1;
    if (tensor == 0) {
      b1 = *(const float4*)(q_bias + h * 64 + d0);
      b2 = *(const float4*)(q_bias + h * 64 + d0 + 32);
    }
    const float sc = (tensor == 0) ? QSCALE : 1.0f;
    float c4[4] = {vc.x, vc.y, vc.z, vc.w};
    float s4[4] = {vs.x, vs.y, vs.z, vs.w};
    float bb1[4] = {b1.x, b1.y, b1.z, b1.w};
    float bb2[4] = {b2.x, b2.y, b2.z, b2.w};
    u16x4 o1, o2;
#pragma unroll
    for (int i = 0; i < 4; ++i) {
      float x1 = bf2f(a1[i]) + bb1[i];
      float x2 = bf2f(a2[i]) + bb2[i];
      o1[i] = f2bf((x1 * c4[i] - x2 * s4[i]) * sc);
      o2[i] = f2bf((x2 * c4[i] + x1 * s4[i]) * sc);
    }
    u16* Out = (tensor == 0) ? Qo : Ko;
    size_t o = ((size_t)(b * 16 + h) * 2048 + l) * 64 + d0;
    *(u16x4*)(Out + o) = o1;
    *(u16x4*)(Out + o + 32) = o2;
  } else {
    int bid2 = bid - 4096;
    int bh = bid2 >> 5;
    int b = bh >> 4, h = bh & 15;
    int l0 = (bid2 & 31) * 64;
    int rr = t >> 2;
    int c0 = (t & 3) * 16;
    const u16* src = qkv + ((size_t)(b * 2048 + l0 + rr)) * 3072 + 2048 + h * 64 + c0;
    u16x8 a = *(const u16x8*)src;
    u16x8 bb = *(const u16x8*)(src + 8);
#pragma unroll
    for (int i = 0; i < 8; ++i) {
      a[i]  = f2bf(bf2f(a[i])  + v_bias[h * 64 + c0 + i]);
      bb[i] = f2bf(bf2f(bb[i]) + v_bias[h * 64 + c0 + 8 + i]);
    }
    *(u16x8*)&tile[rr][c0] = a;
    *(u16x8*)&tile[rr][c0 + 8] = bb;
    __syncthreads();
    int d = t >> 2;
    int lc = (t & 3) * 16;
    u16x8 o1, o2;
#pragma unroll
    for (int i = 0; i < 8; ++i) {
      o1[i] = tile[lc + i][d];
      o2[i] = tile[lc + 8 + i][d];
    }
    u16* dst = vt + ((size_t)bh * 64 + d) * 2048 + l0 + lc;
    *(u16x8*)dst = o1;
    *(u16x8*)(dst + 8) = o2;
  }
}

// ---------------- causal flash attention: 2-tile super-steps (R13, unchanged) ----------
__global__ __launch_bounds__(512)
void attn_kernel(const u16* __restrict__ Q, const u16* __restrict__ Kmat,
                 const u16* __restrict__ Vt, u16* __restrict__ O) {
  __shared__ alignas(16) u16 Ks[4][64 * 64];   // 32 KB
  __shared__ alignas(16) u16 Vs[4][64 * 64];   // 32 KB
  __shared__ alignas(16) u16 Pbuf[8][1024];    // 16 KB
  const int tid = threadIdx.x;
  const int lane = tid & 63;
  const int wave = tid >> 6;                   // 0..7
  const int id = blockIdx.x;
  const int xcd = id & 7, rank = id >> 3;      // rank 0..63
  const int bh = xcd + 8 * (rank & 3);         // 4 bh per XCD -> K/V L2-resident
  const int xqA = 31 - (rank >> 2);            // 16..31, heavy blocks first
  const int wt = wave >> 2;                    // 0 = tile A, 1 = tile B
  const int xq = wt ? (xqA - 16) : xqA;
  const int ntA = xqA + 1;                     // block-level steps (17..32)
  const int nt = xq + 1;                       // this wave's active steps
  const int b = bh >> 4, h = bh & 15;
  const int r = lane & 15, g = lane >> 4;

  const u16* Kb = Kmat + (size_t)bh * 2048 * 64;
  const u16* Vb = Vt + (size_t)bh * 64 * 2048;

  const int srow = wave * 8 + (lane >> 3);
  const int sslot = (lane & 7) ^ (srow & 7);

#define STAGE(tt, bb) do { \
    gload_lds16(Kb + ((size_t)((tt) * 64 + srow)) * 64 + sslot * 8, \
                (char*)Ks[bb] + wave * 1024); \
    gload_lds16(Vb + (size_t)srow * 2048 + (tt) * 64 + sslot * 8, \
                (char*)Vs[bb] + wave * 1024); \
  } while (0)

  u16* Pw = Pbuf[wave];
  const int qrow0 = xq * 64 + (wave & 3) * 16;
  const u16* Qb = Q + ((size_t)bh * 2048 + qrow0) * 64;

  short8 qf[2];
#pragma unroll
  for (int kk = 0; kk < 2; ++kk)
    qf[kk] = *(const short8*)(Qb + r * 64 + kk * 32 + g * 8);

  short8 ones;
#pragma unroll
  for (int i = 0; i < 8; ++i) ones[i] = (short)0x3F80;

  f32x4 o_acc[4] = {};
  f32x4 l_acc = {};

  STAGE(0, 0);
  STAGE(1, 1);
  asm volatile("s_waitcnt vmcnt(0)" ::: "memory");
  __builtin_amdgcn_s_barrier();

  const int nss = (ntA + 1) >> 1;
  for (int ss = 0; ss < nss; ++ss) {
    const int t0 = 2 * ss, t1 = t0 + 1;
    const int cb = 2 * (ss & 1);
    const int sb = 2 * ((ss + 1) & 1);

    if (t0 + 2 < ntA) STAGE(t0 + 2, sb);
    if (t0 + 3 < ntA) STAGE(t0 + 3, sb + 1);

    const bool a0 = (t0 < nt);
    const bool a1 = (t1 < nt);

    f32x4 s0[4] = {}, s1[4] = {};
    __builtin_amdgcn_s_setprio(1);
    if (a0) {
      const char* Kc = (const char*)Ks[cb];
#pragma unroll
      for (int ct = 0; ct < 4; ++ct)
#pragma unroll
        for (int kk = 0; kk < 2; ++kk) {
          int row = ct * 16 + r;
          int byte = row * 128 + (((kk * 4 + g) ^ (row & 7)) << 4);
          short8 kf = *(const short8*)(Kc + byte);
          s0[ct] = __builtin_amdgcn_mfma_f32_16x16x32_bf16(kf, qf[kk], s0[ct], 0, 0, 0);
        }
    }
    if (a1) {
      const char* Kc = (const char*)Ks[cb + 1];
#pragma unroll
      for (int ct = 0; ct < 4; ++ct)
#pragma unroll
        for (int kk = 0; kk < 2; ++kk) {
          int row = ct * 16 + r;
          int byte = row * 128 + (((kk * 4 + g) ^ (row & 7)) << 4);
          short8 kf = *(const short8*)(Kc + byte);
          s1[ct] = __builtin_amdgcn_mfma_f32_16x16x32_bf16(kf, qf[kk], s1[ct], 0, 0, 0);
        }
    }
    __builtin_amdgcn_s_setprio(0);

    if (a0 && t0 * 64 + 63 > qrow0) {
      int qrow = qrow0 + r;
#pragma unroll
      for (int ct = 0; ct < 4; ++ct)
#pragma unroll
        for (int j = 0; j < 4; ++j) {
          int kv = t0 * 64 + ct * 16 + 4 * g + j;
          if (kv > qrow) s0[ct][j] = -1e30f;
        }
    }
    if (a1 && t1 * 64 + 63 > qrow0) {
      int qrow = qrow0 + r;
#pragma unroll
      for (int ct = 0; ct < 4; ++ct)
#pragma unroll
        for (int j = 0; j < 4; ++j) {
          int kv = t1 * 64 + ct * 16 + 4 * g + j;
          if (kv > qrow) s1[ct][j] = -1e30f;
        }
    }

    u32x2 pk0[4], pk1[4];
    if (a0) {
#pragma unroll
      for (int ct = 0; ct < 4; ++ct) {
        float p0 = fexp2(s0[ct][0]);
        float p1 = fexp2(s0[ct][1]);
        float p2 = fexp2(s0[ct][2]);
        float p3 = fexp2(s0[ct][3]);
        asm("v_cvt_pk_bf16_f32 %0, %1, %2" : "=v"(pk0[ct][0]) : "v"(p0), "v"(p1));
        asm("v_cvt_pk_bf16_f32 %0, %1, %2" : "=v"(pk0[ct][1]) : "v"(p2), "v"(p3));
      }
    }
    if (a1) {
#pragma unroll
      for (int ct = 0; ct < 4; ++ct) {
        float p0 = fexp2(s1[ct][0]);
        float p1 = fexp2(s1[ct][1]);
        float p2 = fexp2(s1[ct][2]);
        float p3 = fexp2(s1[ct][3]);
        asm("v_cvt_pk_bf16_f32 %0, %1, %2" : "=v"(pk1[ct][0]) : "v"(p0), "v"(p1));
        asm("v_cvt_pk_bf16_f32 %0, %1, %2" : "=v"(pk1[ct][1]) : "v"(p2), "v"(p3));
      }
    }

    if (a0) {
#pragma unroll
      for (int ct = 0; ct < 4; ++ct) {
        int byte = r * 128 + ((32 * ct + 8 * g) ^ ((r & 7) << 4));
        *(u32x2*)((char*)Pw + byte) = pk0[ct];
      }
      const char* Vc = (const char*)Vs[cb];
      __builtin_amdgcn_s_setprio(1);
#pragma unroll
      for (int kk = 0; kk < 2; ++kk) {
        int byte = r * 128 + (((kk * 4 + g) ^ (r & 7)) << 4);
        short8 pf = *(const short8*)((const char*)Pw + byte);
        l_acc = __builtin_amdgcn_mfma_f32_16x16x32_bf16(pf, ones, l_acc, 0, 0, 0);
#pragma unroll
        for (int n = 0; n < 4; ++n) {
          int row = n * 16 + r;
          int vbyte = row * 128 + (((kk * 4 + g) ^ (row & 7)) << 4);
          short8 vf = *(const short8*)(Vc + vbyte);
          o_acc[n] = __builtin_amdgcn_mfma_f32_16x16x32_bf16(pf, vf, o_acc[n], 0, 0, 0);
        }
      }
      __builtin_amdgcn_s_setprio(0);
    }

    if (a1) {
#pragma unroll
      for (int ct = 0; ct < 4; ++ct) {
        int byte = r * 128 + ((32 * ct + 8 * g) ^ ((r & 7) << 4));
        *(u32x2*)((char*)Pw + byte) = pk1[ct];
      }
      const char* Vc = (const char*)Vs[cb + 1];
      __builtin_amdgcn_s_setprio(1);
#pragma unroll
      for (int kk = 0; kk < 2; ++kk) {
        int byte = r * 128 + (((kk * 4 + g) ^ (r & 7)) << 4);
        short8 pf = *(const short8*)((const char*)Pw + byte);
        l_acc = __builtin_amdgcn_mfma_f32_16x16x32_bf16(pf, ones, l_acc, 0, 0, 0);
#pragma unroll
        for (int n = 0; n < 4; ++n) {
          int row = n * 16 + r;
          int vbyte = row * 128 + (((kk * 4 + g) ^ (row & 7)) << 4);
          short8 vf = *(const short8*)(Vc + vbyte);
          o_acc[n] = __builtin_amdgcn_mfma_f32_16x16x32_bf16(pf, vf, o_acc[n], 0, 0, 0);
        }
      }
      __builtin_amdgcn_s_setprio(0);
    }

    if (ss + 1 < nss) {
      asm volatile("s_waitcnt vmcnt(0)" ::: "memory");
      __builtin_amdgcn_s_barrier();
    }
  }
#undef STAGE

  float ij[4];
#pragma unroll
  for (int j = 0; j < 4; ++j) ij[j] = 1.0f / l_acc[j];
#pragma unroll
  for (int n = 0; n < 4; ++n)
#pragma unroll
    for (int j = 0; j < 4; ++j) {
      size_t idx = ((size_t)b * 2048 + qrow0 + 4 * g + j) * 1024 + h * 64 + n * 16 + r;
      O[idx] = f2bf(o_acc[n][j] * ij[j]);
    }
}

// ---------------- launcher ----------------
extern "C" void kernel_launch(void* const* d_in, const int* in_sizes, int n_in,
                              void* d_out, int out_size, void* d_ws, size_t ws_size,
                              hipStream_t stream) {
  const float* x      = (const float*)d_in[0];
  const int*   pos    = (const int*)d_in[2];
  const float* qkv_w  = (const float*)d_in[3];
  const float* q_bias = (const float*)d_in[4];
  const float* v_bias = (const float*)d_in[5];
  const float* proj_w = (const float*)d_in[6];
  const float* proj_b = (const float*)d_in[7];
  float* out = (float*)d_out;

  char* ws = (char*)d_ws;
  u16* x_bf    = (u16*)(ws + 0);          //  8 MB  [4096][1024]
  u16* w1_bf   = (u16*)(ws + 8388608);    //  6 MB  [3072][1024]
  u16* w2_bf   = (u16*)(ws + 14680064);   //  2 MB  [1024][1024]
  u16* qkv_bf  = (u16*)(ws + 16777216);   // 24 MB  [4096][3072]
  u16* q_bf    = (u16*)(ws + 41943040);   //  8 MB  [B,H,L,D]
  u16* k_bf    = (u16*)(ws + 50331648);   //  8 MB  [B,H,L,D]
  u16* vt_bf   = (u16*)(ws + 58720256);   //  8 MB  [B,H,D,L]
  u16* attn_bf = (u16*)(ws + 67108864);   //  8 MB  [4096][1024]
  float* tab   = (float*)(ws + 75497472); //  1 MB  [B*L][64]

  pre_kernel<<<8704, 256, 0, stream>>>(x, qkv_w, proj_w, pos, x_bf, w1_bf, w2_bf, tab);
  gemm_bt_kernel<true><<<768, 256, 0, stream>>>(x_bf, w1_bf, qkv_bf, nullptr,
                                                4096, 3072, 1024, 24);
  mid_kernel<<<5120, 256, 0, stream>>>(qkv_bf, tab, q_bias, v_bias, q_bf, k_bf, vt_bf);
  attn_kernel<<<512, 512, 0, stream>>>(q_bf, k_bf, vt_bf, attn_bf);
  gemm_bt64_kernel<<<512, 256, 0, stream>>>(attn_bf, w2_bf, out, proj_b,
                                            4096, 1024, 1024, 16);
}

// Round 16
// 105.816 us; speedup vs baseline: 1.1057x; 1.0378x over previous
//
#include <hip/hip_runtime.h>

typedef unsigned short u16;
typedef unsigned int u32;
typedef __attribute__((ext_vector_type(8))) short short8;
typedef __attribute__((ext_vector_type(4))) float f32x4;
typedef __attribute__((ext_vector_type(2))) unsigned int u32x2;
typedef __attribute__((ext_vector_type(4))) unsigned short u16x4;
typedef __attribute__((ext_vector_type(8))) unsigned short u16x8;

#define AS1 __attribute__((address_space(1)))
#define AS3 __attribute__((address_space(3)))

__device__ __forceinline__ u16 f2bf(float f) {
  u32 u = __builtin_bit_cast(u32, f);
  u32 r = u + 0x7FFFu + ((u >> 16) & 1u);
  return (u16)(r >> 16);
}
__device__ __forceinline__ float bf2f(u16 h) {
  u32 u = ((u32)h) << 16;
  return __builtin_bit_cast(float, u);
}
__device__ __forceinline__ void gload_lds16(const void* g, void* l) {
  __builtin_amdgcn_global_load_lds((AS1 void*)g, (AS3 void*)l, 16, 0, 0);
}
__device__ __forceinline__ float fexp2(float x) {
  float r;
  asm("v_exp_f32 %0, %1" : "=v"(r) : "v"(x));
  return r;
}

#define QSCALE 0.04508422002778011f   // (0.25/8) * log2(e)

// ---------------- fused pre-pass: 3x fp32->bf16 convert + RoPE table ----------------
__device__ __forceinline__ void cvt_body(const float* __restrict__ src, u16* __restrict__ dst,
                                         int i) {
  float4 v = ((const float4*)src)[i];
  u16x4 o;
  o[0] = f2bf(v.x); o[1] = f2bf(v.y); o[2] = f2bf(v.z); o[3] = f2bf(v.w);
  ((u16x4*)dst)[i] = o;
}

__global__ __launch_bounds__(256)
void pre_kernel(const float* __restrict__ x, const float* __restrict__ w1,
                const float* __restrict__ w2, const int* __restrict__ pos,
                u16* __restrict__ x_bf, u16* __restrict__ w1_bf, u16* __restrict__ w2_bf,
                float* __restrict__ tab) {
  int bid = blockIdx.x;
  int t = threadIdx.x;
  if (bid < 4096) {
    cvt_body(x, x_bf, bid * 256 + t);
  } else if (bid < 7168) {
    cvt_body(w1, w1_bf, (bid - 4096) * 256 + t);
  } else if (bid < 8192) {
    cvt_body(w2, w2_bf, (bid - 7168) * 256 + t);
  } else {
    int idx = (bid - 8192) * 256 + t;      // over B*L*32 = 131072
    int i = idx & 31;
    int bl = idx >> 5;
    float p = (float)pos[bl];
    float inv_freq = 1.0f / powf(10000.0f, (2.0f * (float)i) / 64.0f);
    float ang = p * inv_freq;
    tab[(size_t)bl * 64 + i] = cosf(ang);
    tab[(size_t)bl * 64 + 32 + i] = sinf(ang);
  }
}

// ---------------- GEMM 128x128: C[M,N] = A[M,K]*B[N,K]^T (+bias opt) ----------------
template <bool OUT_BF16>
__global__ __launch_bounds__(256)
void gemm_bt_kernel(const u16* __restrict__ A, const u16* __restrict__ Bw,
                    void* __restrict__ Cout, const float* __restrict__ bias,
                    int M, int N, int K, int NXT) {
  __shared__ alignas(16) u16 As[128 * 64];
  __shared__ alignas(16) u16 Bs[128 * 64];
  const int tid = threadIdx.x;
  const int lane = tid & 63, wave = tid >> 6;
  const int wr = wave >> 1, wc = wave & 1;
  const int nblk = gridDim.x;
  const int lin = (blockIdx.x & 7) * (nblk >> 3) + (blockIdx.x >> 3);  // XCD-chunked
  const int m0 = (lin / NXT) * 128, n0 = (lin % NXT) * 128;
  const int r = lane & 15, g = lane >> 4;

  f32x4 acc[4][4] = {};

  const int nk = K >> 6;
  for (int kt = 0; kt < nk; ++kt) {
    const int k0 = kt << 6;
#pragma unroll
    for (int c = 0; c < 4; ++c) {
      int i = c * 256 + tid;
      int row = i >> 3, slot = i & 7;
      int ss = slot ^ (row & 7);                       // inverse-swizzled source
      const u16* gA = A + (size_t)(m0 + row) * K + k0 + ss * 8;
      const u16* gB = Bw + (size_t)(n0 + row) * K + k0 + ss * 8;
      void* lA = (char*)As + c * 4096 + wave * 1024;
      void* lB = (char*)Bs + c * 4096 + wave * 1024;
      gload_lds16(gA, lA);
      gload_lds16(gB, lB);
    }
    __syncthreads();
#pragma unroll
    for (int kk = 0; kk < 2; ++kk) {
      short8 af[4], bf[4];
#pragma unroll
      for (int m = 0; m < 4; ++m) {
        int row = wr * 64 + m * 16 + r;
        int byte = row * 128 + (((kk * 4 + g) ^ (row & 7)) << 4);
        af[m] = *(const short8*)((const char*)As + byte);
      }
#pragma unroll
      for (int n = 0; n < 4; ++n) {
        int row = wc * 64 + n * 16 + r;
        int byte = row * 128 + (((kk * 4 + g) ^ (row & 7)) << 4);
        bf[n] = *(const short8*)((const char*)Bs + byte);
      }
#pragma unroll
      for (int m = 0; m < 4; ++m)
#pragma unroll
        for (int n = 0; n < 4; ++n)
          acc[m][n] = __builtin_amdgcn_mfma_f32_16x16x32_bf16(af[m], bf[n], acc[m][n], 0, 0, 0);
    }
    __syncthreads();
  }

  if constexpr (OUT_BF16) {
    u16* C = (u16*)Cout;
#pragma unroll
    for (int m = 0; m < 4; ++m) {
      int rg = m0 + wr * 64 + m * 16 + g * 4;
#pragma unroll
      for (int n = 0; n < 4; ++n) {
        int cg = n0 + wc * 64 + n * 16 + r;
#pragma unroll
        for (int j = 0; j < 4; ++j)
          C[(size_t)(rg + j) * N + cg] = f2bf(acc[m][n][j]);
      }
    }
  } else {
    float* C = (float*)Cout;
#pragma unroll
    for (int m = 0; m < 4; ++m) {
      int rg = m0 + wr * 64 + m * 16 + g * 4;
#pragma unroll
      for (int n = 0; n < 4; ++n) {
        int cg = n0 + wc * 64 + n * 16 + r;
        float bv = bias[cg];
#pragma unroll
        for (int j = 0; j < 4; ++j)
          C[(size_t)(rg + j) * N + cg] = acc[m][n][j] + bv;
      }
    }
  }
}

// ---------------- GEMM 128x64 (proj): 512 blocks -> 2/CU ----------------
__global__ __launch_bounds__(256)
void gemm_bt64_kernel(const u16* __restrict__ A, const u16* __restrict__ Bw,
                      float* __restrict__ Cout, const float* __restrict__ bias,
                      int M, int N, int K, int NXT) {
  __shared__ alignas(16) u16 As[128 * 64];
  __shared__ alignas(16) u16 Bs[64 * 64];
  const int tid = threadIdx.x;
  const int lane = tid & 63, wave = tid >> 6;
  const int wr = wave >> 1, wc = wave & 1;
  const int nblk = gridDim.x;
  const int lin = (blockIdx.x & 7) * (nblk >> 3) + (blockIdx.x >> 3);
  const int m0 = (lin / NXT) * 128, n0 = (lin % NXT) * 64;
  const int r = lane & 15, g = lane >> 4;

  f32x4 acc[4][2] = {};

  const int nk = K >> 6;
  for (int kt = 0; kt < nk; ++kt) {
    const int k0 = kt << 6;
#pragma unroll
    for (int c = 0; c < 4; ++c) {
      int i = c * 256 + tid;
      int row = i >> 3, slot = i & 7;
      int ss = slot ^ (row & 7);
      const u16* gA = A + (size_t)(m0 + row) * K + k0 + ss * 8;
      void* lA = (char*)As + c * 4096 + wave * 1024;
      gload_lds16(gA, lA);
    }
#pragma unroll
    for (int c = 0; c < 2; ++c) {
      int i = c * 256 + tid;
      int row = i >> 3, slot = i & 7;
      int ss = slot ^ (row & 7);
      const u16* gB = Bw + (size_t)(n0 + row) * K + k0 + ss * 8;
      void* lB = (char*)Bs + c * 4096 + wave * 1024;
      gload_lds16(gB, lB);
    }
    __syncthreads();
#pragma unroll
    for (int kk = 0; kk < 2; ++kk) {
      short8 af[4], bf[2];
#pragma unroll
      for (int m = 0; m < 4; ++m) {
        int row = wr * 64 + m * 16 + r;
        int byte = row * 128 + (((kk * 4 + g) ^ (row & 7)) << 4);
        af[m] = *(const short8*)((const char*)As + byte);
      }
#pragma unroll
      for (int n = 0; n < 2; ++n) {
        int row = wc * 32 + n * 16 + r;
        int byte = row * 128 + (((kk * 4 + g) ^ (row & 7)) << 4);
        bf[n] = *(const short8*)((const char*)Bs + byte);
      }
#pragma unroll
      for (int m = 0; m < 4; ++m)
#pragma unroll
        for (int n = 0; n < 2; ++n)
          acc[m][n] = __builtin_amdgcn_mfma_f32_16x16x32_bf16(af[m], bf[n], acc[m][n], 0, 0, 0);
    }
    __syncthreads();
  }

#pragma unroll
  for (int m = 0; m < 4; ++m) {
    int rg = m0 + wr * 64 + m * 16 + g * 4;
#pragma unroll
    for (int n = 0; n < 2; ++n) {
      int cg = n0 + wc * 32 + n * 16 + r;
      float bv = bias[cg];
#pragma unroll
      for (int j = 0; j < 4; ++j)
        Cout[(size_t)(rg + j) * N + cg] = acc[m][n][j] + bv;
    }
  }
}

// ---------------- fused RoPE-pack (vectorized) + V-transpose ----------------
__global__ __launch_bounds__(256)
void mid_kernel(const u16* __restrict__ qkv, const float* __restrict__ tab,
                const float* __restrict__ q_bias, const float* __restrict__ v_bias,
                u16* __restrict__ Qo, u16* __restrict__ Ko, u16* __restrict__ vt) {
  __shared__ alignas(16) u16 tile[64][72];
  int bid = blockIdx.x;
  int t = threadIdx.x;
  if (bid < 4096) {
    int bl = bid;                     // b*2048 + l
    int b = bl >> 11, l = bl & 2047;
    const float* tr = tab + (size_t)bl * 64;
    const u16* base = qkv + (size_t)bl * 3072;
    const int tensor = t >> 7;        // 0 = q, 1 = k
    const int rem = t & 127;
    const int h = rem >> 3;           // 0..15
    const int d0 = (rem & 7) * 4;     // 0,4,..,28
    const u16* src = base + tensor * 1024 + h * 64 + d0;
    u16x4 a1 = *(const u16x4*)src;
    u16x4 a2 = *(const u16x4*)(src + 32);
    float4 vc = *(const float4*)(tr + d0);
    float4 vs = *(const float4*)(tr + 32 + d0);
    float4 b1 = {0.f, 0.f, 0.f, 0.f}, b2 = b1;
    if (tensor == 0) {
      b1 = *(const float4*)(q_bias + h * 64 + d0);
      b2 = *(const float4*)(q_bias + h * 64 + d0 + 32);
    }
    const float sc = (tensor == 0) ? QSCALE : 1.0f;
    float c4[4] = {vc.x, vc.y, vc.z, vc.w};
    float s4[4] = {vs.x, vs.y, vs.z, vs.w};
    float bb1[4] = {b1.x, b1.y, b1.z, b1.w};
    float bb2[4] = {b2.x, b2.y, b2.z, b2.w};
    u16x4 o1, o2;
#pragma unroll
    for (int i = 0; i < 4; ++i) {
      float x1 = bf2f(a1[i]) + bb1[i];
      float x2 = bf2f(a2[i]) + bb2[i];
      o1[i] = f2bf((x1 * c4[i] - x2 * s4[i]) * sc);
      o2[i] = f2bf((x2 * c4[i] + x1 * s4[i]) * sc);
    }
    u16* Out = (tensor == 0) ? Qo : Ko;
    size_t o = ((size_t)(b * 16 + h) * 2048 + l) * 64 + d0;
    *(u16x4*)(Out + o) = o1;
    *(u16x4*)(Out + o + 32) = o2;
  } else {
    int bid2 = bid - 4096;
    int bh = bid2 >> 5;
    int b = bh >> 4, h = bh & 15;
    int l0 = (bid2 & 31) * 64;
    int rr = t >> 2;
    int c0 = (t & 3) * 16;
    const u16* src = qkv + ((size_t)(b * 2048 + l0 + rr)) * 3072 + 2048 + h * 64 + c0;
    u16x8 a = *(const u16x8*)src;
    u16x8 bb = *(const u16x8*)(src + 8);
#pragma unroll
    for (int i = 0; i < 8; ++i) {
      a[i]  = f2bf(bf2f(a[i])  + v_bias[h * 64 + c0 + i]);
      bb[i] = f2bf(bf2f(bb[i]) + v_bias[h * 64 + c0 + 8 + i]);
    }
    *(u16x8*)&tile[rr][c0] = a;
    *(u16x8*)&tile[rr][c0 + 8] = bb;
    __syncthreads();
    int d = t >> 2;
    int lc = (t & 3) * 16;
    u16x8 o1, o2;
#pragma unroll
    for (int i = 0; i < 8; ++i) {
      o1[i] = tile[lc + i][d];
      o2[i] = tile[lc + 8 + i][d];
    }
    u16* dst = vt + ((size_t)bh * 64 + d) * 2048 + l0 + lc;
    *(u16x8*)dst = o1;
    *(u16x8*)(dst + 8) = o2;
  }
}

// ---------------- causal flash attention: split-KV wave groups ----------------
// 1024 blocks x 8 waves. Block = one 64-row q-tile (xq). Waves 0-3 process EVEN kv
// tiles, waves 4-7 ODD kv tiles (static-max softmax => partials merge by ADDITION).
// 4 staging buffers, one vmcnt(0)+barrier per super-step (2 tiles). ~97% wave-slot
// utilization (R13 pairing was ~65%). Group-1 partials merged via LDS at the end.
__global__ __launch_bounds__(512)
void attn_kernel(const u16* __restrict__ Q, const u16* __restrict__ Kmat,
                 const u16* __restrict__ Vt, u16* __restrict__ O) {
  __shared__ alignas(16) u16 Ks[4][64 * 64];   // 32 KB (also reused for the merge)
  __shared__ alignas(16) u16 Vs[4][64 * 64];   // 32 KB
  __shared__ alignas(16) u16 Pbuf[8][1024];    // 16 KB
  const int tid = threadIdx.x;
  const int lane = tid & 63;
  const int wave = tid >> 6;                   // 0..7
  const int grp = wave >> 2;                   // 0: even kv tiles, 1: odd kv tiles
  const int w4 = wave & 3;
  const int id = blockIdx.x;
  const int xcd = id & 7, rank = id >> 3;      // rank 0..127
  const int bh = xcd + 8 * (rank & 3);         // 4 bh per XCD -> K/V L2-resident
  const int xq = 31 - (rank >> 2);             // 31..0, heavy blocks first
  const int nt = xq + 1;                       // kv tiles for this q-tile
  const int nss = (nt + 1) >> 1;               // super-steps
  const int b = bh >> 4, h = bh & 15;
  const int r = lane & 15, g = lane >> 4;

  const u16* Kb = Kmat + (size_t)bh * 2048 * 64;
  const u16* Vb = Vt + (size_t)bh * 64 * 2048;

  const int srow = wave * 8 + (lane >> 3);
  const int sslot = (lane & 7) ^ (srow & 7);

#define STAGE(tt, bb) do { \
    gload_lds16(Kb + ((size_t)((tt) * 64 + srow)) * 64 + sslot * 8, \
                (char*)Ks[bb] + wave * 1024); \
    gload_lds16(Vb + (size_t)srow * 2048 + (tt) * 64 + sslot * 8, \
                (char*)Vs[bb] + wave * 1024); \
  } while (0)

  u16* Pw = Pbuf[wave];
  const int qrow0 = xq * 64 + w4 * 16;
  const u16* Qb = Q + ((size_t)bh * 2048 + qrow0) * 64;

  short8 qf[2];
#pragma unroll
  for (int kk = 0; kk < 2; ++kk)
    qf[kk] = *(const short8*)(Qb + r * 64 + kk * 32 + g * 8);

  short8 ones;
#pragma unroll
  for (int i = 0; i < 8; ++i) ones[i] = (short)0x3F80;

  f32x4 o_acc[4] = {};
  f32x4 l_acc = {};

  // prologue: stage tiles 0,1 into buffers 0,1 (tile 1 may be unused; reads are in-bounds)
  STAGE(0, 0);
  STAGE(1, 1);
  asm volatile("s_waitcnt vmcnt(0)" ::: "memory");
  __builtin_amdgcn_s_barrier();

  for (int ss = 0; ss < nss; ++ss) {
    const int t0 = 2 * ss;
    const int cb = 2 * (ss & 1);               // compute buffer pair
    const int sb = 2 * ((ss + 1) & 1);         // staging buffer pair

    if (t0 + 2 < nt) STAGE(t0 + 2, sb);
    if (t0 + 3 < nt) STAGE(t0 + 3, sb + 1);

    const int t = t0 + grp;                    // this group's tile
    if (t < nt) {
      const char* Kc = (const char*)Ks[cb + grp];
      const char* Vc = (const char*)Vs[cb + grp];
      const int kv0 = t * 64;

      // ---- QK^T (swapped: A=K, B=Q) -> S^T ----
      f32x4 s[4] = {};
      __builtin_amdgcn_s_setprio(1);
#pragma unroll
      for (int ct = 0; ct < 4; ++ct) {
#pragma unroll
        for (int kk = 0; kk < 2; ++kk) {
          int row = ct * 16 + r;
          int byte = row * 128 + (((kk * 4 + g) ^ (row & 7)) << 4);
          short8 kf = *(const short8*)(Kc + byte);
          s[ct] = __builtin_amdgcn_mfma_f32_16x16x32_bf16(kf, qf[kk], s[ct], 0, 0, 0);
        }
      }
      __builtin_amdgcn_s_setprio(0);

      if (kv0 + 63 > qrow0) {                  // diagonal tile -> causal mask (kv > q)
        int qrow = qrow0 + r;
#pragma unroll
        for (int ct = 0; ct < 4; ++ct)
#pragma unroll
          for (int j = 0; j < 4; ++j) {
            int kv = kv0 + ct * 16 + 4 * g + j;
            if (kv > qrow) s[ct][j] = -1e30f;
          }
      }

      // ---- P = exp2(s), pack via v_cvt_pk_bf16_f32 ----
      u32x2 pk[4];
#pragma unroll
      for (int ct = 0; ct < 4; ++ct) {
        float p0 = fexp2(s[ct][0]);
        float p1 = fexp2(s[ct][1]);
        float p2 = fexp2(s[ct][2]);
        float p3 = fexp2(s[ct][3]);
        asm("v_cvt_pk_bf16_f32 %0, %1, %2" : "=v"(pk[ct][0]) : "v"(p0), "v"(p1));
        asm("v_cvt_pk_bf16_f32 %0, %1, %2" : "=v"(pk[ct][1]) : "v"(p2), "v"(p3));
      }

      // ---- P^T -> LDS as [q=r][kv], 4 x ds_write_b64 ----
#pragma unroll
      for (int ct = 0; ct < 4; ++ct) {
        int byte = r * 128 + ((32 * ct + 8 * g) ^ ((r & 7) << 4));
        *(u32x2*)((char*)Pw + byte) = pk[ct];
      }

      // ---- PV from LDS V; l-sum via ones-MFMA ----
      __builtin_amdgcn_s_setprio(1);
#pragma unroll
      for (int kk = 0; kk < 2; ++kk) {
        int byte = r * 128 + (((kk * 4 + g) ^ (r & 7)) << 4);
        short8 pf = *(const short8*)((const char*)Pw + byte);
        l_acc = __builtin_amdgcn_mfma_f32_16x16x32_bf16(pf, ones, l_acc, 0, 0, 0);
#pragma unroll
        for (int n = 0; n < 4; ++n) {
          int row = n * 16 + r;
          int vbyte = row * 128 + (((kk * 4 + g) ^ (row & 7)) << 4);
          short8 vf = *(const short8*)(Vc + vbyte);
          o_acc[n] = __builtin_amdgcn_mfma_f32_16x16x32_bf16(pf, vf, o_acc[n], 0, 0, 0);
        }
      }
      __builtin_amdgcn_s_setprio(0);
    }

    if (ss + 1 < nss) {
      asm volatile("s_waitcnt vmcnt(0)" ::: "memory");  // staged loads (issued this step)
      __builtin_amdgcn_s_barrier();
    }
  }
#undef STAGE

  // ---- merge group partials (static-max => plain addition), then store ----
  // No staged loads are outstanding here (final super-step stages nothing).
  __builtin_amdgcn_s_barrier();                // all compute done; Ks free for reuse
  float* mbase = (float*)(char*)Ks[0];
  float* slot = mbase + (size_t)(w4 * 64 + lane) * 21;   // stride 21 floats: conflict-free
  if (grp == 1) {
#pragma unroll
    for (int n = 0; n < 4; ++n)
#pragma unroll
      for (int j = 0; j < 4; ++j) slot[n * 4 + j] = o_acc[n][j];
#pragma unroll
    for (int j = 0; j < 4; ++j) slot[16 + j] = l_acc[j];
  }
  __builtin_amdgcn_s_barrier();
  if (grp == 0) {
#pragma unroll
    for (int n = 0; n < 4; ++n)
#pragma unroll
      for (int j = 0; j < 4; ++j) o_acc[n][j] += slot[n * 4 + j];
#pragma unroll
    for (int j = 0; j < 4; ++j) l_acc[j] += slot[16 + j];

    float ij[4];
#pragma unroll
    for (int j = 0; j < 4; ++j) ij[j] = 1.0f / l_acc[j];
#pragma unroll
    for (int n = 0; n < 4; ++n)
#pragma unroll
      for (int j = 0; j < 4; ++j) {
        size_t idx = ((size_t)b * 2048 + qrow0 + 4 * g + j) * 1024 + h * 64 + n * 16 + r;
        O[idx] = f2bf(o_acc[n][j] * ij[j]);
      }
  }
}

// ---------------- launcher ----------------
extern "C" void kernel_launch(void* const* d_in, const int* in_sizes, int n_in,
                              void* d_out, int out_size, void* d_ws, size_t ws_size,
                              hipStream_t stream) {
  const float* x      = (const float*)d_in[0];
  const int*   pos    = (const int*)d_in[2];
  const float* qkv_w  = (const float*)d_in[3];
  const float* q_bias = (const float*)d_in[4];
  const float* v_bias = (const float*)d_in[5];
  const float* proj_w = (const float*)d_in[6];
  const float* proj_b = (const float*)d_in[7];
  float* out = (float*)d_out;

  char* ws = (char*)d_ws;
  u16* x_bf    = (u16*)(ws + 0);          //  8 MB  [4096][1024]
  u16* w1_bf   = (u16*)(ws + 8388608);    //  6 MB  [3072][1024]
  u16* w2_bf   = (u16*)(ws + 14680064);   //  2 MB  [1024][1024]
  u16* qkv_bf  = (u16*)(ws + 16777216);   // 24 MB  [4096][3072]
  u16* q_bf    = (u16*)(ws + 41943040);   //  8 MB  [B,H,L,D]
  u16* k_bf    = (u16*)(ws + 50331648);   //  8 MB  [B,H,L,D]
  u16* vt_bf   = (u16*)(ws + 58720256);   //  8 MB  [B,H,D,L]
  u16* attn_bf = (u16*)(ws + 67108864);   //  8 MB  [4096][1024]
  float* tab   = (float*)(ws + 75497472); //  1 MB  [B*L][64]

  pre_kernel<<<8704, 256, 0, stream>>>(x, qkv_w, proj_w, pos, x_bf, w1_bf, w2_bf, tab);
  gemm_bt_kernel<true><<<768, 256, 0, stream>>>(x_bf, w1_bf, qkv_bf, nullptr,
                                                4096, 3072, 1024, 24);
  mid_kernel<<<5120, 256, 0, stream>>>(qkv_bf, tab, q_bias, v_bias, q_bf, k_bf, vt_bf);
  attn_kernel<<<1024, 512, 0, stream>>>(q_bf, k_bf, vt_bf, attn_bf);
  gemm_bt64_kernel<<<512, 256, 0, stream>>>(attn_bf, w2_bf, out, proj_b,
                                            4096, 1024, 1024, 16);
}